// Round 9
// baseline (341.218 us; speedup 1.0000x reference)
//
#include <hip/hip_runtime.h>
#include <hip/hip_bf16.h>

#define D_DIM 768
#define F_DIM 16384
#define M_CONN 262144
#define N_ROWS 1024   // B*S = 2*512

typedef float f32x4 __attribute__((ext_vector_type(4)));
typedef unsigned short u16x4 __attribute__((ext_vector_type(4)));

__device__ __forceinline__ float bf2f(unsigned short u) {
    return __uint_as_float(((unsigned int)u) << 16);
}

// ---------------------------------------------------------------------------
// fp32 -> bf16 transpose, 256x128 tile, 512 threads, REGISTER-STAGED loads:
// all 16 NT loads issued before any consumer, so the wave pays the ~900-cyc
// HBM latency once instead of 16 times (theory: prior versions serialized
// on per-iteration vmcnt waits, capping them at ~1.3 TB/s).
// Grid: dim3(C/128, R/256). in [R][C] fp32 -> out [C][R] bf16.
// ---------------------------------------------------------------------------
__global__ __launch_bounds__(512, 4) void transpose_f2b_t(const float* __restrict__ in,
                                                          unsigned short* __restrict__ out,
                                                          int R, int C) {
    __shared__ unsigned short ldsT[128][260];  // [c][r]
    const int t = threadIdx.x;
    const int x0 = blockIdx.x * 128;   // in-col origin
    const int y0 = blockIdx.y * 256;   // in-row origin
    f32x4 v[16];
#pragma unroll
    for (int it = 0; it < 16; ++it) {
        const int idx = it * 512 + t;          // 0..8191
        const int r = idx >> 5;                // 0..255
        const int c4 = idx & 31;               // cols c4*4..+3
        v[it] = __builtin_nontemporal_load(
            (const f32x4*)(in + (size_t)(y0 + r) * C + x0 + c4 * 4));
    }
#pragma unroll
    for (int it = 0; it < 16; ++it) {
        const int idx = it * 512 + t;
        const int r = idx >> 5;
        const int c4 = idx & 31;
        __hip_bfloat16 b0 = __float2bfloat16(v[it].x);
        __hip_bfloat16 b1 = __float2bfloat16(v[it].y);
        __hip_bfloat16 b2 = __float2bfloat16(v[it].z);
        __hip_bfloat16 b3 = __float2bfloat16(v[it].w);
        ldsT[c4 * 4 + 0][r] = *(unsigned short*)&b0;
        ldsT[c4 * 4 + 1][r] = *(unsigned short*)&b1;
        ldsT[c4 * 4 + 2][r] = *(unsigned short*)&b2;
        ldsT[c4 * 4 + 3][r] = *(unsigned short*)&b3;
    }
    __syncthreads();
#pragma unroll
    for (int it = 0; it < 16; ++it) {
        const int idx = it * 512 + t;          // 0..8191
        const int c = idx >> 6;                // 0..127
        const int r4 = idx & 63;               // rows r4*4..+3
        const u16x4 o = *(const u16x4*)&ldsT[c][r4 * 4];
        *(u16x4*)(out + (size_t)(x0 + c) * R + y0 + r4 * 4) = o;
    }
}

// ---------------------------------------------------------------------------
// bf16 -> fp32 transpose, 128x256 tile, 512 threads, REGISTER-STAGED loads,
// NT both ways. Grid: dim3(C'/256, R'/128). in [R'][C'] bf16 -> out fp32.
// ---------------------------------------------------------------------------
__global__ __launch_bounds__(512, 4) void transpose_b2f_t(const unsigned short* __restrict__ in,
                                                          float* __restrict__ out,
                                                          int R, int C) {
    __shared__ unsigned short ldsT[256][130];  // [c][r], r<128
    const int t = threadIdx.x;
    const int x0 = blockIdx.x * 256;   // in-col origin (r-dim of outT)
    const int y0 = blockIdx.y * 128;   // in-row origin (i-dim)
    u16x4 v[16];
#pragma unroll
    for (int it = 0; it < 16; ++it) {
        const int idx = it * 512 + t;          // 0..8191
        const int r = idx >> 6;                // 0..127 (in-row)
        const int c4 = idx & 63;               // cols c4*4..+3
        v[it] = __builtin_nontemporal_load(
            (const u16x4*)(in + (size_t)(y0 + r) * C + x0 + c4 * 4));
    }
#pragma unroll
    for (int it = 0; it < 16; ++it) {
        const int idx = it * 512 + t;
        const int r = idx >> 6;
        const int c4 = idx & 63;
        ldsT[c4 * 4 + 0][r] = v[it].x;
        ldsT[c4 * 4 + 1][r] = v[it].y;
        ldsT[c4 * 4 + 2][r] = v[it].z;
        ldsT[c4 * 4 + 3][r] = v[it].w;
    }
    __syncthreads();
#pragma unroll
    for (int it = 0; it < 16; ++it) {
        const int idx = it * 512 + t;          // 0..8191
        const int c = idx >> 5;                // 0..255 (out-row)
        const int r4 = idx & 31;               // rows r4*4..+3
        const u16x4 o = *(const u16x4*)&ldsT[c][r4 * 4];
        f32x4 f;
        f.x = bf2f(o.x); f.y = bf2f(o.y); f.z = bf2f(o.z); f.w = bf2f(o.w);
        __builtin_nontemporal_store(
            f, (f32x4*)(out + (size_t)(x0 + c) * R + y0 + r4 * 4));
    }
}

// ---------------------------------------------------------------------------
// values[m] = dot(de[i_m, :], udT[j_m, :]) over D=768, udT in bf16.
// m0 = half offset: launched 2x with M/2 each (visibility split).
// ---------------------------------------------------------------------------
__global__ __launch_bounds__(256) void values_kernel(const float* __restrict__ de,
                                                     const unsigned short* __restrict__ udT,
                                                     const int* __restrict__ i_idx,
                                                     const int* __restrict__ j_idx,
                                                     float* __restrict__ values,
                                                     int m0) {
    const int wave = (blockIdx.x * blockDim.x + threadIdx.x) >> 6;
    const int lane = threadIdx.x & 63;
    const int mbase = m0 + wave * 4;

    int ii[4], jj[4];
#pragma unroll
    for (int t = 0; t < 4; ++t) {
        ii[t] = i_idx[mbase + t];
        jj[t] = j_idx[mbase + t];
    }
    ushort4 u[4][3];
#pragma unroll
    for (int t = 0; t < 4; ++t) {
        const ushort4* b = (const ushort4*)(udT + (size_t)jj[t] * D_DIM);
        u[t][0] = b[lane]; u[t][1] = b[lane + 64]; u[t][2] = b[lane + 128];
    }

    int cur_i = -1;
    float4 a0, a1, a2;
#pragma unroll
    for (int t = 0; t < 4; ++t) {
        const int i = ii[t];
        if (i != cur_i) {  // wave-uniform (i uniform across lanes)
            const float4* a = (const float4*)(de + (size_t)i * D_DIM);
            a0 = a[lane]; a1 = a[lane + 64]; a2 = a[lane + 128];
            cur_i = i;
        }
        float s = 0.f;
        s = fmaf(a0.x, bf2f(u[t][0].x), s); s = fmaf(a0.y, bf2f(u[t][0].y), s);
        s = fmaf(a0.z, bf2f(u[t][0].z), s); s = fmaf(a0.w, bf2f(u[t][0].w), s);
        s = fmaf(a1.x, bf2f(u[t][1].x), s); s = fmaf(a1.y, bf2f(u[t][1].y), s);
        s = fmaf(a1.z, bf2f(u[t][1].z), s); s = fmaf(a1.w, bf2f(u[t][1].w), s);
        s = fmaf(a2.x, bf2f(u[t][2].x), s); s = fmaf(a2.y, bf2f(u[t][2].y), s);
        s = fmaf(a2.z, bf2f(u[t][2].z), s); s = fmaf(a2.w, bf2f(u[t][2].w), s);
#pragma unroll
        for (int off = 32; off > 0; off >>= 1)
            s += __shfl_down(s, off, 64);
        if (lane == 0) values[mbase + t] = s;
    }
}

// ---------------------------------------------------------------------------
// seg[i] = lower_bound(i_idx, M, i); seg[F] = M.
// ---------------------------------------------------------------------------
__global__ __launch_bounds__(256) void seg_kernel(const int* __restrict__ i_idx,
                                                  int* __restrict__ seg) {
    const int i = blockIdx.x * blockDim.x + threadIdx.x;
    if (i > F_DIM) return;
    if (i == F_DIM) { seg[i] = M_CONN; return; }
    int lo = 0, hi = M_CONN;
    while (lo < hi) {
        int mid = (lo + hi) >> 1;
        if (i_idx[mid] < i) lo = mid + 1; else hi = mid;
    }
    seg[i] = lo;
}

// ---------------------------------------------------------------------------
// SpMM (R6 structure). i0 = quarter offset (4 dispatches, visibility split).
// ---------------------------------------------------------------------------
__global__ __launch_bounds__(256) void spmm_kernel(const unsigned short* __restrict__ upT,
                                                   const int* __restrict__ j_idx,
                                                   const float* __restrict__ vals,
                                                   const int* __restrict__ seg,
                                                   unsigned short* __restrict__ outT,
                                                   int i0) {
    const int i = i0 + blockIdx.x;
    const int t = threadIdx.x;
    const int ms = seg[i], me = seg[i + 1];
    float4 acc0 = make_float4(0.f, 0.f, 0.f, 0.f);
    float4 acc1 = make_float4(0.f, 0.f, 0.f, 0.f);
    float4 acc2 = make_float4(0.f, 0.f, 0.f, 0.f);
    float4 acc3 = make_float4(0.f, 0.f, 0.f, 0.f);
    int m = ms;
    for (; m + 3 < me; m += 4) {
        const int j0 = j_idx[m],     j1 = j_idx[m + 1];
        const int j2 = j_idx[m + 2], j3 = j_idx[m + 3];
        const float v0 = vals[m],     v1 = vals[m + 1];
        const float v2 = vals[m + 2], v3 = vals[m + 3];
        const ushort4 x0 = ((const ushort4*)(upT + (size_t)j0 * N_ROWS))[t];
        const ushort4 x1 = ((const ushort4*)(upT + (size_t)j1 * N_ROWS))[t];
        const ushort4 x2 = ((const ushort4*)(upT + (size_t)j2 * N_ROWS))[t];
        const ushort4 x3 = ((const ushort4*)(upT + (size_t)j3 * N_ROWS))[t];
        acc0.x = fmaf(v0, bf2f(x0.x), acc0.x); acc0.y = fmaf(v0, bf2f(x0.y), acc0.y);
        acc0.z = fmaf(v0, bf2f(x0.z), acc0.z); acc0.w = fmaf(v0, bf2f(x0.w), acc0.w);
        acc1.x = fmaf(v1, bf2f(x1.x), acc1.x); acc1.y = fmaf(v1, bf2f(x1.y), acc1.y);
        acc1.z = fmaf(v1, bf2f(x1.z), acc1.z); acc1.w = fmaf(v1, bf2f(x1.w), acc1.w);
        acc2.x = fmaf(v2, bf2f(x2.x), acc2.x); acc2.y = fmaf(v2, bf2f(x2.y), acc2.y);
        acc2.z = fmaf(v2, bf2f(x2.z), acc2.z); acc2.w = fmaf(v2, bf2f(x2.w), acc2.w);
        acc3.x = fmaf(v3, bf2f(x3.x), acc3.x); acc3.y = fmaf(v3, bf2f(x3.y), acc3.y);
        acc3.z = fmaf(v3, bf2f(x3.z), acc3.z); acc3.w = fmaf(v3, bf2f(x3.w), acc3.w);
    }
    for (; m < me; ++m) {
        const int j0 = j_idx[m];
        const float v0 = vals[m];
        const ushort4 x0 = ((const ushort4*)(upT + (size_t)j0 * N_ROWS))[t];
        acc0.x = fmaf(v0, bf2f(x0.x), acc0.x); acc0.y = fmaf(v0, bf2f(x0.y), acc0.y);
        acc0.z = fmaf(v0, bf2f(x0.z), acc0.z); acc0.w = fmaf(v0, bf2f(x0.w), acc0.w);
    }
    const float rx = (acc0.x + acc1.x) + (acc2.x + acc3.x);
    const float ry = (acc0.y + acc1.y) + (acc2.y + acc3.y);
    const float rz = (acc0.z + acc1.z) + (acc2.z + acc3.z);
    const float rw = (acc0.w + acc1.w) + (acc2.w + acc3.w);
    __hip_bfloat16 b0 = __float2bfloat16(rx);
    __hip_bfloat16 b1 = __float2bfloat16(ry);
    __hip_bfloat16 b2 = __float2bfloat16(rz);
    __hip_bfloat16 b3 = __float2bfloat16(rw);
    u16x4 o;
    o.x = *(unsigned short*)&b0;
    o.y = *(unsigned short*)&b1;
    o.z = *(unsigned short*)&b2;
    o.w = *(unsigned short*)&b3;
    __builtin_nontemporal_store(o, (u16x4*)(outT + (size_t)i * N_ROWS) + t);
}

// ---------------------------------------------------------------------------
// Buffer plan (ws ~65.1 MB) — ALL REGIONS DISJOINT:
//   ws + 0     : udT  bf16 [F,768]  24 MB   (stages 1-2)
//   ws + 24 MB : outT bf16 [F,1024] 32 MB   (stages 5-6)
//   ws + 64 MB : values [M] fp32, 1 MB
//   ws + 65 MB : seg [F+1] int, 64 KB
//   d_out      : upT bf16 [F,1024] 32 MB (stages 3-5), then final out fp32
// ---------------------------------------------------------------------------
extern "C" void kernel_launch(void* const* d_in, const int* in_sizes, int n_in,
                              void* d_out, int out_size, void* d_ws, size_t ws_size,
                              hipStream_t stream) {
    const float* up_facts = (const float*)d_in[0];   // [1024, F]
    const float* de       = (const float*)d_in[1];   // [F, D]
    const float* ud       = (const float*)d_in[2];   // [D, F]
    const int*   i_idx    = (const int*)d_in[3];     // [M] sorted
    const int*   j_idx    = (const int*)d_in[4];     // [M]
    float* out = (float*)d_out;

    char* ws = (char*)d_ws;
    unsigned short* udT  = (unsigned short*)ws;                          // bf16 [F,768]
    unsigned short* outT = (unsigned short*)(ws + (size_t)24 * 1024 * 1024); // bf16 [F,1024]
    float* values = (float*)(ws + (size_t)64 * 1024 * 1024);             // 1 MB
    int*   seg    = (int*)  (ws + (size_t)65 * 1024 * 1024);             // 64 KB + 4
    unsigned short* upT = (unsigned short*)out;                          // bf16 [F,1024]

    // 1) udT = bf16(ud^T): in [768][16384] -> out [16384][768]
    transpose_f2b_t<<<dim3(F_DIM / 128, D_DIM / 256), 512, 0, stream>>>(
        ud, udT, D_DIM, F_DIM);
    // 2) values[m] = <de[i_m], udT[j_m]> — 2 half-dispatches (visibility)
    for (int h = 0; h < 2; ++h)
        values_kernel<<<(M_CONN / 8) * 64 / 256, 256, 0, stream>>>(
            de, udT, i_idx, j_idx, values, h * (M_CONN / 2));
    // 3) upT = bf16(up_facts^T): in [1024][16384] -> out [16384][1024]
    transpose_f2b_t<<<dim3(F_DIM / 128, N_ROWS / 256), 512, 0, stream>>>(
        up_facts, upT, N_ROWS, F_DIM);
    // 4) CSR row pointers
    seg_kernel<<<(F_DIM + 1 + 255) / 256, 256, 0, stream>>>(i_idx, seg);
    // 5) outT[i] = bf16( sum v * upT[j] ) — 4 quarter-dispatches (visibility)
    for (int q = 0; q < 4; ++q)
        spmm_kernel<<<F_DIM / 4, 256, 0, stream>>>(upT, j_idx, values, seg, outT,
                                                   q * (F_DIM / 4));
    // 6) out = fp32(outT^T): in [16384][1024] bf16 -> out [1024][16384] fp32
    transpose_b2f_t<<<dim3(N_ROWS / 256, F_DIM / 128), 512, 0, stream>>>(
        outT, out, F_DIM, N_ROWS);
}

// Round 10
// 323.653 us; speedup vs baseline: 1.0543x; 1.0543x over previous
//
#include <hip/hip_runtime.h>
#include <hip/hip_bf16.h>

#define D_DIM 768
#define F_DIM 16384
#define M_CONN 262144
#define N_ROWS 1024   // B*S = 2*512

typedef float f32x4 __attribute__((ext_vector_type(4)));
typedef unsigned short u16x4 __attribute__((ext_vector_type(4)));

__device__ __forceinline__ float bf2f(unsigned short u) {
    return __uint_as_float(((unsigned int)u) << 16);
}

// ---------------------------------------------------------------------------
// FUSED fp32 -> bf16 transposes for BOTH inputs in ONE dispatch (saves a
// ~10 us graph-node gap). blockIdx.y < yA: job A (ud [768][16384] -> udT);
// else job B (up [1024][16384] -> upT). 256x128 tile, 512 threads,
// register-staged NT loads (R9).
// Grid: dim3(C/128, yA + yB), C = 16384 for both jobs.
// ---------------------------------------------------------------------------
__global__ __launch_bounds__(512, 4) void transpose_f2b_fused(
        const float* __restrict__ inA, unsigned short* __restrict__ outA, int RA, int yA,
        const float* __restrict__ inB, unsigned short* __restrict__ outB, int RB) {
    const int C = F_DIM;
    const float* in;
    unsigned short* out;
    int R, yb;
    if (blockIdx.y < (unsigned)yA) { in = inA; out = outA; R = RA; yb = blockIdx.y; }
    else                           { in = inB; out = outB; R = RB; yb = blockIdx.y - yA; }

    __shared__ unsigned short ldsT[128][260];  // [c][r]
    const int t = threadIdx.x;
    const int x0 = blockIdx.x * 128;   // in-col origin
    const int y0 = yb * 256;           // in-row origin
    f32x4 v[16];
#pragma unroll
    for (int it = 0; it < 16; ++it) {
        const int idx = it * 512 + t;          // 0..8191
        const int r = idx >> 5;                // 0..255
        const int c4 = idx & 31;               // cols c4*4..+3
        v[it] = __builtin_nontemporal_load(
            (const f32x4*)(in + (size_t)(y0 + r) * C + x0 + c4 * 4));
    }
#pragma unroll
    for (int it = 0; it < 16; ++it) {
        const int idx = it * 512 + t;
        const int r = idx >> 5;
        const int c4 = idx & 31;
        __hip_bfloat16 b0 = __float2bfloat16(v[it].x);
        __hip_bfloat16 b1 = __float2bfloat16(v[it].y);
        __hip_bfloat16 b2 = __float2bfloat16(v[it].z);
        __hip_bfloat16 b3 = __float2bfloat16(v[it].w);
        ldsT[c4 * 4 + 0][r] = *(unsigned short*)&b0;
        ldsT[c4 * 4 + 1][r] = *(unsigned short*)&b1;
        ldsT[c4 * 4 + 2][r] = *(unsigned short*)&b2;
        ldsT[c4 * 4 + 3][r] = *(unsigned short*)&b3;
    }
    __syncthreads();
#pragma unroll
    for (int it = 0; it < 16; ++it) {
        const int idx = it * 512 + t;          // 0..8191
        const int c = idx >> 6;                // 0..127
        const int r4 = idx & 63;               // rows r4*4..+3
        const u16x4 o = *(const u16x4*)&ldsT[c][r4 * 4];
        *(u16x4*)(out + (size_t)(x0 + c) * R + y0 + r4 * 4) = o;
    }
}

// ---------------------------------------------------------------------------
// bf16 -> fp32 transpose, 128x256 tile, 512 threads, register-staged NT
// loads, NT stores. Grid: dim3(C'/256, R'/128). in [R'][C'] bf16 -> fp32.
// ---------------------------------------------------------------------------
__global__ __launch_bounds__(512, 4) void transpose_b2f_t(const unsigned short* __restrict__ in,
                                                          float* __restrict__ out,
                                                          int R, int C) {
    __shared__ unsigned short ldsT[256][130];  // [c][r], r<128
    const int t = threadIdx.x;
    const int x0 = blockIdx.x * 256;   // in-col origin (r-dim of outT)
    const int y0 = blockIdx.y * 128;   // in-row origin (i-dim)
    u16x4 v[16];
#pragma unroll
    for (int it = 0; it < 16; ++it) {
        const int idx = it * 512 + t;          // 0..8191
        const int r = idx >> 6;                // 0..127 (in-row)
        const int c4 = idx & 63;               // cols c4*4..+3
        v[it] = __builtin_nontemporal_load(
            (const u16x4*)(in + (size_t)(y0 + r) * C + x0 + c4 * 4));
    }
#pragma unroll
    for (int it = 0; it < 16; ++it) {
        const int idx = it * 512 + t;
        const int r = idx >> 6;
        const int c4 = idx & 63;
        ldsT[c4 * 4 + 0][r] = v[it].x;
        ldsT[c4 * 4 + 1][r] = v[it].y;
        ldsT[c4 * 4 + 2][r] = v[it].z;
        ldsT[c4 * 4 + 3][r] = v[it].w;
    }
    __syncthreads();
#pragma unroll
    for (int it = 0; it < 16; ++it) {
        const int idx = it * 512 + t;          // 0..8191
        const int c = idx >> 5;                // 0..255 (out-row)
        const int r4 = idx & 31;               // rows r4*4..+3
        const u16x4 o = *(const u16x4*)&ldsT[c][r4 * 4];
        f32x4 f;
        f.x = bf2f(o.x); f.y = bf2f(o.y); f.z = bf2f(o.z); f.w = bf2f(o.w);
        __builtin_nontemporal_store(
            f, (f32x4*)(out + (size_t)(x0 + c) * R + y0 + r4 * 4));
    }
}

// ---------------------------------------------------------------------------
// values[m] = dot(de[i_m, :], udT[j_m, :]) over D=768, udT in bf16 — PLUS
// fused CSR row-pointer construction: lane 0 of each wave scatters
// seg[k] = m at every i_idx step (sorted i => exact lower_bound), replacing
// the separate seg_kernel (saves a graph node).
// ---------------------------------------------------------------------------
__global__ __launch_bounds__(256) void values_kernel(const float* __restrict__ de,
                                                     const unsigned short* __restrict__ udT,
                                                     const int* __restrict__ i_idx,
                                                     const int* __restrict__ j_idx,
                                                     float* __restrict__ values,
                                                     int* __restrict__ seg) {
    const int wave = (blockIdx.x * blockDim.x + threadIdx.x) >> 6;
    const int lane = threadIdx.x & 63;
    const int mbase = wave * 4;

    int ii[4], jj[4];
#pragma unroll
    for (int t = 0; t < 4; ++t) {
        ii[t] = i_idx[mbase + t];
        jj[t] = j_idx[mbase + t];
    }

    // --- fused seg construction (lane 0 only; avg <1 store per wave) ---
    if (lane == 0) {
        int prev = (mbase == 0) ? -1 : i_idx[mbase - 1];
#pragma unroll
        for (int t = 0; t < 4; ++t) {
            const int cur = ii[t];
            for (int k = prev + 1; k <= cur; ++k) seg[k] = mbase + t;
            prev = cur;
        }
        if (mbase + 4 == M_CONN)
            for (int k = prev + 1; k <= F_DIM; ++k) seg[k] = M_CONN;
    }

    ushort4 u[4][3];
#pragma unroll
    for (int t = 0; t < 4; ++t) {
        const ushort4* b = (const ushort4*)(udT + (size_t)jj[t] * D_DIM);
        u[t][0] = b[lane]; u[t][1] = b[lane + 64]; u[t][2] = b[lane + 128];
    }

    int cur_i = -1;
    float4 a0, a1, a2;
#pragma unroll
    for (int t = 0; t < 4; ++t) {
        const int i = ii[t];
        if (i != cur_i) {  // wave-uniform (i uniform across lanes)
            const float4* a = (const float4*)(de + (size_t)i * D_DIM);
            a0 = a[lane]; a1 = a[lane + 64]; a2 = a[lane + 128];
            cur_i = i;
        }
        float s = 0.f;
        s = fmaf(a0.x, bf2f(u[t][0].x), s); s = fmaf(a0.y, bf2f(u[t][0].y), s);
        s = fmaf(a0.z, bf2f(u[t][0].z), s); s = fmaf(a0.w, bf2f(u[t][0].w), s);
        s = fmaf(a1.x, bf2f(u[t][1].x), s); s = fmaf(a1.y, bf2f(u[t][1].y), s);
        s = fmaf(a1.z, bf2f(u[t][1].z), s); s = fmaf(a1.w, bf2f(u[t][1].w), s);
        s = fmaf(a2.x, bf2f(u[t][2].x), s); s = fmaf(a2.y, bf2f(u[t][2].y), s);
        s = fmaf(a2.z, bf2f(u[t][2].z), s); s = fmaf(a2.w, bf2f(u[t][2].w), s);
#pragma unroll
        for (int off = 32; off > 0; off >>= 1)
            s += __shfl_down(s, off, 64);
        if (lane == 0) values[mbase + t] = s;
    }
}

// ---------------------------------------------------------------------------
// SpMM (R6 structure, proven): outT[i,:] = sum_m v_m * upT[j_m,:].
// One 256-thread block per i; 4-way unroll; fp32 acc; bf16 NT output.
// ---------------------------------------------------------------------------
__global__ __launch_bounds__(256) void spmm_kernel(const unsigned short* __restrict__ upT,
                                                   const int* __restrict__ j_idx,
                                                   const float* __restrict__ vals,
                                                   const int* __restrict__ seg,
                                                   unsigned short* __restrict__ outT) {
    const int i = blockIdx.x;
    const int t = threadIdx.x;
    const int ms = seg[i], me = seg[i + 1];
    float4 acc0 = make_float4(0.f, 0.f, 0.f, 0.f);
    float4 acc1 = make_float4(0.f, 0.f, 0.f, 0.f);
    float4 acc2 = make_float4(0.f, 0.f, 0.f, 0.f);
    float4 acc3 = make_float4(0.f, 0.f, 0.f, 0.f);
    int m = ms;
    for (; m + 3 < me; m += 4) {
        const int j0 = j_idx[m],     j1 = j_idx[m + 1];
        const int j2 = j_idx[m + 2], j3 = j_idx[m + 3];
        const float v0 = vals[m],     v1 = vals[m + 1];
        const float v2 = vals[m + 2], v3 = vals[m + 3];
        const ushort4 x0 = ((const ushort4*)(upT + (size_t)j0 * N_ROWS))[t];
        const ushort4 x1 = ((const ushort4*)(upT + (size_t)j1 * N_ROWS))[t];
        const ushort4 x2 = ((const ushort4*)(upT + (size_t)j2 * N_ROWS))[t];
        const ushort4 x3 = ((const ushort4*)(upT + (size_t)j3 * N_ROWS))[t];
        acc0.x = fmaf(v0, bf2f(x0.x), acc0.x); acc0.y = fmaf(v0, bf2f(x0.y), acc0.y);
        acc0.z = fmaf(v0, bf2f(x0.z), acc0.z); acc0.w = fmaf(v0, bf2f(x0.w), acc0.w);
        acc1.x = fmaf(v1, bf2f(x1.x), acc1.x); acc1.y = fmaf(v1, bf2f(x1.y), acc1.y);
        acc1.z = fmaf(v1, bf2f(x1.z), acc1.z); acc1.w = fmaf(v1, bf2f(x1.w), acc1.w);
        acc2.x = fmaf(v2, bf2f(x2.x), acc2.x); acc2.y = fmaf(v2, bf2f(x2.y), acc2.y);
        acc2.z = fmaf(v2, bf2f(x2.z), acc2.z); acc2.w = fmaf(v2, bf2f(x2.w), acc2.w);
        acc3.x = fmaf(v3, bf2f(x3.x), acc3.x); acc3.y = fmaf(v3, bf2f(x3.y), acc3.y);
        acc3.z = fmaf(v3, bf2f(x3.z), acc3.z); acc3.w = fmaf(v3, bf2f(x3.w), acc3.w);
    }
    for (; m < me; ++m) {
        const int j0 = j_idx[m];
        const float v0 = vals[m];
        const ushort4 x0 = ((const ushort4*)(upT + (size_t)j0 * N_ROWS))[t];
        acc0.x = fmaf(v0, bf2f(x0.x), acc0.x); acc0.y = fmaf(v0, bf2f(x0.y), acc0.y);
        acc0.z = fmaf(v0, bf2f(x0.z), acc0.z); acc0.w = fmaf(v0, bf2f(x0.w), acc0.w);
    }
    const float rx = (acc0.x + acc1.x) + (acc2.x + acc3.x);
    const float ry = (acc0.y + acc1.y) + (acc2.y + acc3.y);
    const float rz = (acc0.z + acc1.z) + (acc2.z + acc3.z);
    const float rw = (acc0.w + acc1.w) + (acc2.w + acc3.w);
    __hip_bfloat16 b0 = __float2bfloat16(rx);
    __hip_bfloat16 b1 = __float2bfloat16(ry);
    __hip_bfloat16 b2 = __float2bfloat16(rz);
    __hip_bfloat16 b3 = __float2bfloat16(rw);
    u16x4 o;
    o.x = *(unsigned short*)&b0;
    o.y = *(unsigned short*)&b1;
    o.z = *(unsigned short*)&b2;
    o.w = *(unsigned short*)&b3;
    __builtin_nontemporal_store(o, (u16x4*)(outT + (size_t)i * N_ROWS) + t);
}

// ---------------------------------------------------------------------------
// Buffer plan (ws ~65.1 MB) — ALL REGIONS DISJOINT:
//   ws + 0     : udT  bf16 [F,768]  24 MB   (stages 1-2)
//   ws + 24 MB : outT bf16 [F,1024] 32 MB   (stages 3-4)
//   ws + 64 MB : values [M] fp32, 1 MB
//   ws + 65 MB : seg [F+1] int, 64 KB
//   d_out      : upT bf16 [F,1024] 32 MB (stages 1-3), then final out fp32
// 4 graph nodes total (was 10): fused transposes, values+seg, spmm, b2f.
// ---------------------------------------------------------------------------
extern "C" void kernel_launch(void* const* d_in, const int* in_sizes, int n_in,
                              void* d_out, int out_size, void* d_ws, size_t ws_size,
                              hipStream_t stream) {
    const float* up_facts = (const float*)d_in[0];   // [1024, F]
    const float* de       = (const float*)d_in[1];   // [F, D]
    const float* ud       = (const float*)d_in[2];   // [D, F]
    const int*   i_idx    = (const int*)d_in[3];     // [M] sorted
    const int*   j_idx    = (const int*)d_in[4];     // [M]
    float* out = (float*)d_out;

    char* ws = (char*)d_ws;
    unsigned short* udT  = (unsigned short*)ws;                              // bf16 [F,768]
    unsigned short* outT = (unsigned short*)(ws + (size_t)24 * 1024 * 1024); // bf16 [F,1024]
    float* values = (float*)(ws + (size_t)64 * 1024 * 1024);                 // 1 MB
    int*   seg    = (int*)  (ws + (size_t)65 * 1024 * 1024);                 // 64 KB + 4
    unsigned short* upT = (unsigned short*)out;                              // bf16 [F,1024]

    // 1) udT = bf16(ud^T)  AND  upT = bf16(up_facts^T), one dispatch.
    //    job A: ud [768][16384] -> udT, 3 y-blocks; job B: up [1024][16384] -> upT, 4 y-blocks.
    transpose_f2b_fused<<<dim3(F_DIM / 128, D_DIM / 256 + N_ROWS / 256), 512, 0, stream>>>(
        ud, udT, D_DIM, D_DIM / 256, up_facts, upT, N_ROWS);
    // 2) values[m] = <de[i_m], udT[j_m]>  +  fused seg construction
    values_kernel<<<(M_CONN / 4) * 64 / 256, 256, 0, stream>>>(
        de, udT, i_idx, j_idx, values, seg);
    // 3) outT[i] = bf16( sum v * upT[j] )
    spmm_kernel<<<F_DIM, 256, 0, stream>>>(upT, j_idx, values, seg, outT);
    // 4) out = fp32(outT^T): in [16384][1024] bf16 -> out [1024][16384] fp32
    transpose_b2f_t<<<dim3(N_ROWS / 256, F_DIM / 128), 512, 0, stream>>>(
        outT, out, F_DIM, N_ROWS);
}